// Round 1
// baseline (775.808 us; speedup 1.0000x reference)
//
#include <hip/hip_runtime.h>
#include <cstdint>
#include <cstddef>

// Problem constants
constexpr int cB = 8, cC = 256, cT = 16000, cN = 32;
constexpr int cP = 80;            // time chunks per sequence
constexpr int cLAM = cT / cP;     // 200, chunk length (must be %4==0)
static_assert(cLAM % 4 == 0, "chunk length must be multiple of 4");
constexpr float cEPS = 1e-8f;

typedef __bf16 bf16;
typedef __bf16 bf16x8 __attribute__((ext_vector_type(8)));
typedef float floatx4 __attribute__((ext_vector_type(4)));

// Workspace layout (bytes), all 16B-aligned
constexpr size_t kMean = 0;                              // B*T floats
constexpr size_t kRstd = kMean + (size_t)cB * cT * 4;    // B*T floats
constexpr size_t kWr   = kRstd + (size_t)cB * cT * 4;    // C*N floats each:
constexpr size_t kWi   = kWr  + (size_t)cC * cN * 4;
constexpr size_t kC2r  = kWi  + (size_t)cC * cN * 4;
constexpr size_t kC2i  = kC2r + (size_t)cC * cN * 4;
constexpr size_t kWlr  = kC2i + (size_t)cC * cN * 4;
constexpr size_t kWli  = kWlr + (size_t)cC * cN * 4;
constexpr size_t kWb   = kWli + (size_t)cC * cN * 4;     // 512*256 bf16
constexpr size_t kS    = kWb  + (size_t)512 * 256 * 2;   // B*C*P*N*2 floats
constexpr size_t kU    = kS   + (size_t)cB * cC * cP * cN * 2 * 4; // B*T*C bf16

// ---------------- prep: S4D discretization params + W -> bf16 ----------------
__global__ void prep_kernel(const float* __restrict__ log_dt,
                            const float* __restrict__ log_A_real,
                            const float* __restrict__ A_imag,
                            const float* __restrict__ C_re,
                            const float* __restrict__ C_im,
                            const float* __restrict__ W_out,
                            float* __restrict__ wr, float* __restrict__ wi,
                            float* __restrict__ c2r, float* __restrict__ c2i,
                            float* __restrict__ wlr, float* __restrict__ wli,
                            bf16* __restrict__ Wb) {
  int idx = blockIdx.x * 256 + threadIdx.x;
  if (idx < 512 * 256) Wb[idx] = (bf16)W_out[idx];
  if (idx < cC * cN) {
    int c = idx >> 5;
    double dt = exp((double)log_dt[c]);
    double Ar = -exp((double)log_A_real[idx]);
    double Ai = (double)A_imag[idx];
    double dtAr = dt * Ar, dtAi = dt * Ai;
    double mg = exp(dtAr);
    double wre = mg * cos(dtAi), wim = mg * sin(dtAi);
    double den = Ar * Ar + Ai * Ai;
    double emr = wre - 1.0, emi = wim;           // exp(dtA) - 1
    double qr = (emr * Ar + emi * Ai) / den;     // (exp(dtA)-1)/A
    double qi = (emi * Ar - emr * Ai) / den;
    double cre = (double)C_re[idx], cim = (double)C_im[idx];
    c2r[idx] = (float)(2.0 * (cre * qr - cim * qi));
    c2i[idx] = (float)(2.0 * (cre * qi + cim * qr));
    wr[idx] = (float)wre; wi[idx] = (float)wim;
    double mL = exp((double)cLAM * dtAr), phL = (double)cLAM * dtAi;
    wlr[idx] = (float)(mL * cos(phL));
    wli[idx] = (float)(mL * sin(phL));
  }
}

// ---------------- stats: per-(b,t) mean / rstd over C ----------------
__global__ void stats_kernel(const float* __restrict__ x,
                             float* __restrict__ meanp, float* __restrict__ rstdp) {
  int g = blockIdx.x * 256 + threadIdx.x;   // 0 .. B*T-1
  int b = g / cT;
  int t = g - b * cT;
  const float* xp = x + (size_t)b * cC * cT + t;
  float s1 = 0.f, s2 = 0.f;
#pragma unroll 8
  for (int c = 0; c < cC; ++c) {
    float v = xp[(size_t)c * cT];
    s1 += v;
    s2 = fmaf(v, v, s2);
  }
  float mean = s1 * (1.0f / cC);
  float var = fmaf(s2, 1.0f / cC, -mean * mean);
  meanp[g] = mean;
  rstdp[g] = rsqrtf(var + cEPS);
}

// ---------------- scan pass A: per-chunk local final states ----------------
__global__ __launch_bounds__(256, 2)
void scanA_kernel(const float* __restrict__ x, const float* __restrict__ meanp,
                  const float* __restrict__ rstdp, const float* __restrict__ gam,
                  const float* __restrict__ bet, const float* __restrict__ prw,
                  const float* __restrict__ wrp, const float* __restrict__ wip,
                  float* __restrict__ S) {
  int blk = blockIdx.x;              // b*cP + p
  int b = blk / cP, p = blk - b * cP;
  int c = threadIdx.x;
  float gamma = gam[c], beta = bet[c], pw = prw[c];
  float wr[cN], wi[cN], hre[cN], him[cN];
#pragma unroll
  for (int n = 0; n < cN; ++n) {
    wr[n] = wrp[c * cN + n]; wi[n] = wip[c * cN + n];
    hre[n] = 0.f; him[n] = 0.f;
  }
  const float* xp = x + (size_t)(b * cC + c) * cT + p * cLAM;
  const float* mp = meanp + (size_t)b * cT + p * cLAM;
  const float* rp = rstdp + (size_t)b * cT + p * cLAM;
  for (int j = 0; j < cLAM; j += 4) {
    float4 xv = *(const float4*)(xp + j);
    float4 mv = *(const float4*)(mp + j);
    float4 rv = *(const float4*)(rp + j);
    float xs[4] = {xv.x, xv.y, xv.z, xv.w};
    float ms[4] = {mv.x, mv.y, mv.z, mv.w};
    float rs[4] = {rv.x, rv.y, rv.z, rv.w};
#pragma unroll
    for (int s = 0; s < 4; ++s) {
      float y = fmaf((xs[s] - ms[s]) * rs[s], gamma, beta);
      y = y >= 0.f ? y : y * pw;
#pragma unroll
      for (int n = 0; n < cN; ++n) {
        float t1 = fmaf(wr[n], hre[n], y);
        float nh = fmaf(-wi[n], him[n], t1);
        float ni = fmaf(wr[n], him[n], wi[n] * hre[n]);
        hre[n] = nh; him[n] = ni;
      }
    }
  }
  float* sp = S + (size_t)((b * cC + c) * cP + p) * cN * 2;
#pragma unroll
  for (int n = 0; n < cN; ++n) { sp[2 * n] = hre[n]; sp[2 * n + 1] = him[n]; }
}

// ---------------- prefix over chunks (in place: S(p) -> Hinit(p)) ----------------
__global__ void prefix_kernel(const float* __restrict__ wlrp, const float* __restrict__ wlip,
                              float* __restrict__ S) {
  int id = blockIdx.x * 256 + threadIdx.x;  // 0 .. B*C*N-1
  int n = id & (cN - 1);
  int c = (id >> 5) & (cC - 1);
  int b = id >> 13;
  float wr = wlrp[c * cN + n], wi = wlip[c * cN + n];
  float hr = 0.f, hi = 0.f;
  float* base = S + (size_t)(b * cC + c) * cP * cN * 2 + n * 2;
  for (int p = 0; p < cP; ++p) {
    float* a = base + (size_t)p * cN * 2;
    float sr = a[0], si = a[1];
    a[0] = hr; a[1] = hi;
    float nr = fmaf(wr, hr, fmaf(-wi, hi, sr));
    float ni = fmaf(wr, hi, fmaf(wi, hr, si));
    hr = nr; hi = ni;
  }
}

// ---------------- scan pass B: full scan + skip + GELU -> u[b,t,c] bf16 ----------------
__global__ __launch_bounds__(256, 2)
void scanB_kernel(const float* __restrict__ x, const float* __restrict__ meanp,
                  const float* __restrict__ rstdp, const float* __restrict__ gam,
                  const float* __restrict__ bet, const float* __restrict__ prw,
                  const float* __restrict__ Dp, const float* __restrict__ wrp,
                  const float* __restrict__ wip, const float* __restrict__ c2rp,
                  const float* __restrict__ c2ip, const float* __restrict__ S,
                  bf16* __restrict__ U) {
  int blk = blockIdx.x;
  int b = blk / cP, p = blk - b * cP;
  int c = threadIdx.x;
  float gamma = gam[c], beta = bet[c], pw = prw[c], Dc = Dp[c];
  float wr[cN], wi[cN], cr[cN], nci[cN], hre[cN], him[cN];
  const float* sp = S + (size_t)((b * cC + c) * cP + p) * cN * 2;
#pragma unroll
  for (int n = 0; n < cN; ++n) {
    wr[n] = wrp[c * cN + n]; wi[n] = wip[c * cN + n];
    cr[n] = c2rp[c * cN + n]; nci[n] = -c2ip[c * cN + n];
    hre[n] = sp[2 * n]; him[n] = sp[2 * n + 1];
  }
  const float* xp = x + (size_t)(b * cC + c) * cT + p * cLAM;
  const float* mp = meanp + (size_t)b * cT + p * cLAM;
  const float* rp = rstdp + (size_t)b * cT + p * cLAM;
  bf16* up = U + ((size_t)b * cT + p * cLAM) * cC + c;
  for (int j = 0; j < cLAM; j += 4) {
    float4 xv = *(const float4*)(xp + j);
    float4 mv = *(const float4*)(mp + j);
    float4 rv = *(const float4*)(rp + j);
    float xs[4] = {xv.x, xv.y, xv.z, xv.w};
    float ms[4] = {mv.x, mv.y, mv.z, mv.w};
    float rs[4] = {rv.x, rv.y, rv.z, rv.w};
#pragma unroll
    for (int s = 0; s < 4; ++s) {
      float y = fmaf((xs[s] - ms[s]) * rs[s], gamma, beta);
      y = y >= 0.f ? y : y * pw;
      float acc = 0.f;
#pragma unroll
      for (int n = 0; n < cN; ++n) {
        float t1 = fmaf(wr[n], hre[n], y);
        float nh = fmaf(-wi[n], him[n], t1);
        float ni = fmaf(wr[n], him[n], wi[n] * hre[n]);
        hre[n] = nh; him[n] = ni;
        acc = fmaf(cr[n], nh, acc);
        acc = fmaf(nci[n], ni, acc);
      }
      float sv = fmaf(Dc, y, acc);                       // + D * y skip
      float g = 0.5f * sv * (1.0f + erff(sv * 0.70710678118654752f));
      up[(size_t)(j + s) * cC] = (bf16)g;
    }
  }
}

// ---------------- GEMM: z = W_out @ u, +bias, GLU, +residual ----------------
// u: [B*T, 256] bf16, Wb: [512, 256] bf16.  MFMA 16x16x32 bf16.
// A frag: A[m=lane&15][k=quad*8+j]; B frag: B[k=quad*8+j][n=lane&15];
// D: col=lane&15, row=quad*4+reg.
__global__ __launch_bounds__(1024, 4)
void gemm_kernel(const bf16* __restrict__ U, const bf16* __restrict__ Wb,
                 const float* __restrict__ b_out, const float* __restrict__ x,
                 float* __restrict__ out) {
  int lane = threadIdx.x & 63;
  int w = threadIdx.x >> 6;       // 0..15 -> c-tile
  int m = lane & 15;
  int quad = lane >> 4;
  int c0 = w * 16;
  const bf16* a1p = Wb + (size_t)(c0 + m) * 256 + quad * 8;
  const bf16* a2p = a1p + (size_t)256 * 256;
  bf16x8 a1[8], a2[8];
#pragma unroll
  for (int s = 0; s < 8; ++s) {
    a1[s] = *(const bf16x8*)(a1p + s * 32);
    a2[s] = *(const bf16x8*)(a2p + s * 32);
  }
  int btbase = blockIdx.x * 128;
  int b = btbase / cT;            // tiles never straddle b (16000 % 128 == 0)
  int tbase = btbase - b * cT;
#pragma unroll 1
  for (int tt = 0; tt < 8; ++tt) {
    int bt0 = btbase + tt * 16;
    const bf16* bp = U + (size_t)(bt0 + m) * 256 + quad * 8;
    floatx4 acc1 = {0.f, 0.f, 0.f, 0.f};
    floatx4 acc2 = {0.f, 0.f, 0.f, 0.f};
#pragma unroll
    for (int s = 0; s < 8; ++s) {
      bf16x8 bfrag = *(const bf16x8*)(bp + s * 32);
      acc1 = __builtin_amdgcn_mfma_f32_16x16x32_bf16(a1[s], bfrag, acc1, 0, 0, 0);
      acc2 = __builtin_amdgcn_mfma_f32_16x16x32_bf16(a2[s], bfrag, acc2, 0, 0, 0);
    }
    int t = tbase + tt * 16 + m;
#pragma unroll
    for (int r = 0; r < 4; ++r) {
      int cc = c0 + quad * 4 + r;
      float z1 = acc1[r] + b_out[cc];
      float z2 = acc2[r] + b_out[cc + 256];
      float sg = 1.0f / (1.0f + expf(-z2));
      size_t idx = (size_t)(b * cC + cc) * cT + t;
      out[idx] = x[idx] + z1 * sg;
    }
  }
}

extern "C" void kernel_launch(void* const* d_in, const int* in_sizes, int n_in,
                              void* d_out, int out_size, void* d_ws, size_t ws_size,
                              hipStream_t stream) {
  const float* x          = (const float*)d_in[0];
  const float* gamma      = (const float*)d_in[1];
  const float* beta       = (const float*)d_in[2];
  const float* prelu_w    = (const float*)d_in[3];
  const float* log_dt     = (const float*)d_in[4];
  const float* log_A_real = (const float*)d_in[5];
  const float* A_imag     = (const float*)d_in[6];
  const float* C_re       = (const float*)d_in[7];
  const float* C_im       = (const float*)d_in[8];
  const float* Dp         = (const float*)d_in[9];
  const float* W_out      = (const float*)d_in[10];
  const float* b_out      = (const float*)d_in[11];
  float* out = (float*)d_out;
  char* ws = (char*)d_ws;

  float* meanp = (float*)(ws + kMean);
  float* rstdp = (float*)(ws + kRstd);
  float* wr    = (float*)(ws + kWr);
  float* wi    = (float*)(ws + kWi);
  float* c2r   = (float*)(ws + kC2r);
  float* c2i   = (float*)(ws + kC2i);
  float* wlr   = (float*)(ws + kWlr);
  float* wli   = (float*)(ws + kWli);
  bf16*  Wb    = (bf16*)(ws + kWb);
  float* S     = (float*)(ws + kS);
  bf16*  U     = (bf16*)(ws + kU);

  prep_kernel<<<512, 256, 0, stream>>>(log_dt, log_A_real, A_imag, C_re, C_im,
                                       W_out, wr, wi, c2r, c2i, wlr, wli, Wb);
  stats_kernel<<<(cB * cT) / 256, 256, 0, stream>>>(x, meanp, rstdp);
  scanA_kernel<<<cB * cP, 256, 0, stream>>>(x, meanp, rstdp, gamma, beta,
                                            prelu_w, wr, wi, S);
  prefix_kernel<<<(cB * cC * cN) / 256, 256, 0, stream>>>(wlr, wli, S);
  scanB_kernel<<<cB * cP, 256, 0, stream>>>(x, meanp, rstdp, gamma, beta,
                                            prelu_w, Dp, wr, wi, c2r, c2i, S, U);
  gemm_kernel<<<(cB * cT) / 128, 1024, 0, stream>>>(U, Wb, b_out, x, out);
}

// Round 2
// 492.223 us; speedup vs baseline: 1.5761x; 1.5761x over previous
//
#include <hip/hip_runtime.h>
#include <cstdint>
#include <cstddef>

// Problem constants
constexpr int cB = 8, cC = 256, cT = 16000, cN = 32;
constexpr int cLAM = 128;          // chunk length (MFMA-friendly)
constexpr int cP = 125;            // chunks per sequence (125*128 = 16000)
constexpr int cPpad = 128;         // padded chunk-row count
constexpr float cEPS = 1e-8f;

typedef __bf16 bf16;
typedef __bf16 bf16x4 __attribute__((ext_vector_type(4)));
typedef __bf16 bf16x8 __attribute__((ext_vector_type(8)));
typedef float floatx4 __attribute__((ext_vector_type(4)));

// Workspace layout (bytes), all 16B-aligned
constexpr size_t kMean = 0;                                // B*T f32
constexpr size_t kRstd = kMean + (size_t)cB * cT * 4;      // B*T f32
constexpr size_t kWlr  = kRstd + (size_t)cB * cT * 4;      // C*32 f32 (w^128 re)
constexpr size_t kWli  = kWlr + (size_t)cC * cN * 4;       // C*32 f32 (w^128 im)
constexpr size_t kWb   = kWli + (size_t)cC * cN * 4;       // 512*256 bf16
constexpr size_t kLt   = kWb  + (size_t)512 * 256 * 2;     // C*128*128 bf16 (Toeplitz, row j: k[j-i])
constexpr size_t kEt   = kLt  + (size_t)cC * 128 * 128 * 2;// C*64*128 bf16 (state extraction)
constexpr size_t kVt   = kEt  + (size_t)cC * 64 * 128 * 2; // C*128*64 bf16 (correction)
constexpr size_t kU    = kVt  + (size_t)cC * 128 * 64 * 2; // B*C*T bf16 (u, [b][c][t])

// ---------------- prepW: W_out -> bf16 ----------------
__global__ void prepW_kernel(const float* __restrict__ W_out, bf16* __restrict__ Wb) {
  int idx = blockIdx.x * 256 + threadIdx.x;
  if (idx < 512 * 256) Wb[idx] = (bf16)W_out[idx];
}

// ---------------- prep2: per-channel S4D matrices (Lt, Et, Vt, w^128) ----------------
__global__ void prep2_kernel(const float* __restrict__ log_dt,
                             const float* __restrict__ log_A_real,
                             const float* __restrict__ A_imag,
                             const float* __restrict__ C_re,
                             const float* __restrict__ C_im,
                             float* __restrict__ wlr, float* __restrict__ wli,
                             bf16* __restrict__ Lt, bf16* __restrict__ Et,
                             bf16* __restrict__ Vt) {
  int c = blockIdx.x;        // 256 blocks
  int j = threadIdx.x;       // 128 threads
  __shared__ float kv[128];
  float dt = expf(log_dt[c]);
  float kj = 0.f;
  for (int n = 0; n < cN; ++n) {
    int idx = c * cN + n;
    float Ar = -expf(log_A_real[idx]);
    float Ai = A_imag[idx];
    float ar = dt * Ar, ai = dt * Ai;           // dtA
    // w = exp(dtA)
    float mg = expf(ar), cw, sw;
    sincosf(ai, &sw, &cw);
    float wre = mg * cw, wim = mg * sw;
    // Cc2 = 2*C*(exp(dtA)-1)/A
    float den = Ar * Ar + Ai * Ai;
    float emr = wre - 1.f, emi = wim;
    float qr = (emr * Ar + emi * Ai) / den;
    float qi = (emi * Ar - emr * Ai) / den;
    float cre = C_re[idx], cim = C_im[idx];
    float c2r = 2.f * (cre * qr - cim * qi);
    float c2i = 2.f * (cre * qi + cim * qr);
    // w^j
    float mj = expf((float)j * ar), cj, sj;
    sincosf((float)j * ai, &sj, &cj);
    float wjr = mj * cj, wji = mj * sj;
    kj += c2r * wjr - c2i * wji;                 // k[j] = Re(Cc2 * w^j)
    // w^{j+1} = w^j * w
    float w1r = wjr * wre - wji * wim;
    float w1i = wjr * wim + wji * wre;
    Vt[(size_t)c * 8192 + j * 64 + 2 * n]     = (bf16)(c2r * w1r - c2i * w1i);
    Vt[(size_t)c * 8192 + j * 64 + 2 * n + 1] = (bf16)(-(c2r * w1i + c2i * w1r));
    // w^{127-j}
    float mr = expf((float)(127 - j) * ar), cr2, sr2;
    sincosf((float)(127 - j) * ai, &sr2, &cr2);
    Et[(size_t)c * 8192 + (2 * n) * 128 + j]     = (bf16)(mr * cr2);
    Et[(size_t)c * 8192 + (2 * n + 1) * 128 + j] = (bf16)(mr * sr2);
  }
  kv[j] = kj;
  if (j < cN) {      // w^128 for the chunk prefix
    int idx = c * cN + j;
    float Ar = -expf(log_A_real[idx]);
    float ai = dt * A_imag[idx], ar = dt * Ar;
    float m = expf(128.f * ar), cc, ss;
    sincosf(128.f * ai, &ss, &cc);
    wlr[idx] = m * cc;
    wli[idx] = m * ss;
  }
  __syncthreads();
  // Lt row j: Lt[j][i] = k[j-i] for i<=j else 0
  bf16* row = Lt + (size_t)c * 16384 + (size_t)j * 128;
  for (int i = 0; i < 128; i += 4) {
    bf16x4 v;
    for (int q = 0; q < 4; ++q) {
      int ii = i + q;
      v[q] = (ii <= j) ? (bf16)kv[j - ii] : (bf16)0.f;
    }
    *(bf16x4*)(row + i) = v;
  }
}

// ---------------- stats: per-(b,t) mean / rstd over C ----------------
__global__ void stats_kernel(const float* __restrict__ x,
                             float* __restrict__ meanp, float* __restrict__ rstdp) {
  int g = blockIdx.x * 256 + threadIdx.x;   // 0 .. B*T-1
  int b = g / cT;
  int t = g - b * cT;
  const float* xp = x + (size_t)b * cC * cT + t;
  float s1 = 0.f, s2 = 0.f;
#pragma unroll 8
  for (int c = 0; c < cC; ++c) {
    float v = xp[(size_t)c * cT];
    s1 += v;
    s2 = fmaf(v, v, s2);
  }
  float mean = s1 * (1.0f / cC);
  float var = fmaf(s2, 1.0f / cC, -mean * mean);
  meanp[g] = mean;
  rstdp[g] = rsqrtf(var + cEPS);
}

// ---------------- scanM: LN+PReLU -> MFMA chunked scan -> skip -> GELU -> U[b][c][t] ----------------
// Per block: one (b,c). Y in LDS [128 rows(p)][136], chunk conv = Y*Lt^T,
// states = Y*Et^T, segmented prefix in-block, correction = Hin*Vt^T (bf16 hi/lo).
__global__ __launch_bounds__(256, 2)
void scanM_kernel(const float* __restrict__ x, const float* __restrict__ meanp,
                  const float* __restrict__ rstdp, const float* __restrict__ gam,
                  const float* __restrict__ bet, const float* __restrict__ prw,
                  const float* __restrict__ Dp,
                  const float* __restrict__ wlr, const float* __restrict__ wli,
                  const bf16* __restrict__ Lt, const bf16* __restrict__ Et,
                  const bf16* __restrict__ Vt, bf16* __restrict__ U) {
  __shared__ __align__(16) bf16 Y[128 * 136];
  __shared__ __align__(16) bf16 H[128 * 136];
  __shared__ float Sseg[8][32][2];

  int blk = blockIdx.x;
  int b = blk & 7, c = blk >> 3;          // c-major: 8 sibling blocks share matrices in L2
  int tid = threadIdx.x;
  int lane = tid & 63, w = tid >> 6, quad = lane >> 4, mh = lane & 15;
  float gamma = gam[c], beta = bet[c], pw = prw[c], Dc = Dp[c];

  // ---- phase 1: y = PReLU(LN(x)) -> Y LDS (bf16) ----
  const float4* x4 = (const float4*)(x + (size_t)(b * cC + c) * cT);
  const float4* m4 = (const float4*)(meanp + (size_t)b * cT);
  const float4* r4 = (const float4*)(rstdp + (size_t)b * cT);
#pragma unroll
  for (int it = 0; it < 16; ++it) {
    int i4 = tid + it * 256;
    if (i4 < 4000) {
      float4 xv = x4[i4], mv = m4[i4], rv = r4[i4];
      int t = i4 * 4, p = t >> 7, j = t & 127;
      float ys[4];
      ys[0] = fmaf((xv.x - mv.x) * rv.x, gamma, beta);
      ys[1] = fmaf((xv.y - mv.y) * rv.y, gamma, beta);
      ys[2] = fmaf((xv.z - mv.z) * rv.z, gamma, beta);
      ys[3] = fmaf((xv.w - mv.w) * rv.w, gamma, beta);
      bf16x4 yv;
#pragma unroll
      for (int q = 0; q < 4; ++q) {
        float y = ys[q];
        yv[q] = (bf16)(y >= 0.f ? y : y * pw);
      }
      *(bf16x4*)&Y[p * 136 + j] = yv;
    }
  }
  for (int e = tid; e < 3 * 136; e += 256) Y[125 * 136 + e] = (bf16)0.f;  // pad rows
  __syncthreads();

  // ---- phase 2: extraction H[p][comp] = sum_i Y[p][i]*Et[comp][i]; store bf16 hi/lo ----
  const bf16* EtC = Et + (size_t)c * 8192;
  floatx4 hacc[8];
#pragma unroll
  for (int mi = 0; mi < 8; ++mi) hacc[mi] = (floatx4){0.f, 0.f, 0.f, 0.f};
#pragma unroll
  for (int kk = 0; kk < 4; ++kk) {
    bf16x8 bfrag = *(const bf16x8*)(EtC + (w * 16 + mh) * 128 + kk * 32 + quad * 8);
#pragma unroll
    for (int mi = 0; mi < 8; ++mi) {
      bf16x8 af = *(bf16x8*)&Y[(mi * 16 + mh) * 136 + kk * 32 + quad * 8];
      hacc[mi] = __builtin_amdgcn_mfma_f32_16x16x32_bf16(af, bfrag, hacc[mi], 0, 0, 0);
    }
  }
#pragma unroll
  for (int mi = 0; mi < 8; ++mi) {
#pragma unroll
    for (int r = 0; r < 4; ++r) {
      int p = mi * 16 + quad * 4 + r;
      int comp = w * 16 + mh;
      float v = hacc[mi][r];
      bf16 hi = (bf16)v;
      bf16 lo = (bf16)(v - (float)hi);
      H[p * 136 + comp] = hi;
      H[p * 136 + 64 + comp] = lo;
    }
  }
  __syncthreads();

  // ---- phase 3: segmented prefix over chunks (exclusive), in place ----
  {
    int n = tid & 31, sg = tid >> 5;
    int p0 = sg * 16;
    int p1 = (p0 + 16 < cP) ? p0 + 16 : cP;
    float wr = wlr[c * cN + n], wi = wli[c * cN + n];
    float hR = 0.f, hI = 0.f;
    for (int p = p0; p < p1; ++p) {
      float sr = (float)H[p * 136 + 2 * n] + (float)H[p * 136 + 64 + 2 * n];
      float si = (float)H[p * 136 + 2 * n + 1] + (float)H[p * 136 + 64 + 2 * n + 1];
      float t1 = fmaf(wr, hR, fmaf(-wi, hI, sr));
      hI = fmaf(wr, hI, fmaf(wi, hR, si));
      hR = t1;
    }
    Sseg[sg][n][0] = hR; Sseg[sg][n][1] = hI;
    __syncthreads();
    if (tid < 32) {
      float ar = wr, ai = wi;       // (w^128)^16 via 4 squarings
      for (int q = 0; q < 4; ++q) {
        float nr = ar * ar - ai * ai;
        ai = 2.f * ar * ai; ar = nr;
      }
      float HR = 0.f, HI = 0.f;
      for (int s2 = 0; s2 < 8; ++s2) {
        float fr = Sseg[s2][n][0], fi = Sseg[s2][n][1];
        Sseg[s2][n][0] = HR; Sseg[s2][n][1] = HI;
        float t1 = fmaf(ar, HR, fmaf(-ai, HI, fr));
        HI = fmaf(ar, HI, fmaf(ai, HR, fi));
        HR = t1;
      }
    }
    __syncthreads();
    hR = Sseg[sg][n][0]; hI = Sseg[sg][n][1];
    for (int p = p0; p < p1; ++p) {
      float sr = (float)H[p * 136 + 2 * n] + (float)H[p * 136 + 64 + 2 * n];
      float si = (float)H[p * 136 + 2 * n + 1] + (float)H[p * 136 + 64 + 2 * n + 1];
      bf16 hiR = (bf16)hR; bf16 loR = (bf16)(hR - (float)hiR);
      bf16 hiI = (bf16)hI; bf16 loI = (bf16)(hI - (float)hiI);
      H[p * 136 + 2 * n] = hiR;      H[p * 136 + 2 * n + 1] = hiI;
      H[p * 136 + 64 + 2 * n] = loR; H[p * 136 + 64 + 2 * n + 1] = loI;
      float t1 = fmaf(wr, hR, fmaf(-wi, hI, sr));
      hI = fmaf(wr, hI, fmaf(wi, hR, si));
      hR = t1;
    }
  }
  __syncthreads();

  // ---- phase 4: s = Y*Lt^T + Hin*Vt^T (hi+lo), + D*y, GELU ----
  const bf16* LtC = Lt + (size_t)c * 16384;
  const bf16* VtC = Vt + (size_t)c * 8192;
  floatx4 acc[8][2];
#pragma unroll
  for (int mi = 0; mi < 8; ++mi) {
    acc[mi][0] = (floatx4){0.f, 0.f, 0.f, 0.f};
    acc[mi][1] = (floatx4){0.f, 0.f, 0.f, 0.f};
  }
#pragma unroll
  for (int kk = 0; kk < 4; ++kk) {
    bf16x8 b0 = *(const bf16x8*)(LtC + ((2 * w) * 16 + mh) * 128 + kk * 32 + quad * 8);
    bf16x8 b1 = *(const bf16x8*)(LtC + ((2 * w + 1) * 16 + mh) * 128 + kk * 32 + quad * 8);
#pragma unroll
    for (int mi = 0; mi < 8; ++mi) {
      bf16x8 af = *(bf16x8*)&Y[(mi * 16 + mh) * 136 + kk * 32 + quad * 8];
      acc[mi][0] = __builtin_amdgcn_mfma_f32_16x16x32_bf16(af, b0, acc[mi][0], 0, 0, 0);
      acc[mi][1] = __builtin_amdgcn_mfma_f32_16x16x32_bf16(af, b1, acc[mi][1], 0, 0, 0);
    }
  }
#pragma unroll
  for (int kk = 0; kk < 2; ++kk) {
    bf16x8 v0 = *(const bf16x8*)(VtC + ((2 * w) * 16 + mh) * 64 + kk * 32 + quad * 8);
    bf16x8 v1 = *(const bf16x8*)(VtC + ((2 * w + 1) * 16 + mh) * 64 + kk * 32 + quad * 8);
#pragma unroll
    for (int mi = 0; mi < 8; ++mi) {
      bf16x8 ah = *(bf16x8*)&H[(mi * 16 + mh) * 136 + kk * 32 + quad * 8];
      bf16x8 al = *(bf16x8*)&H[(mi * 16 + mh) * 136 + 64 + kk * 32 + quad * 8];
      acc[mi][0] = __builtin_amdgcn_mfma_f32_16x16x32_bf16(ah, v0, acc[mi][0], 0, 0, 0);
      acc[mi][1] = __builtin_amdgcn_mfma_f32_16x16x32_bf16(ah, v1, acc[mi][1], 0, 0, 0);
      acc[mi][0] = __builtin_amdgcn_mfma_f32_16x16x32_bf16(al, v0, acc[mi][0], 0, 0, 0);
      acc[mi][1] = __builtin_amdgcn_mfma_f32_16x16x32_bf16(al, v1, acc[mi][1], 0, 0, 0);
    }
  }
  // epilogue: u = GELU(s + D*y) (held in regs across the barrier)
  bf16 ub[8][2][4];
#pragma unroll
  for (int mi = 0; mi < 8; ++mi)
#pragma unroll
    for (int jj = 0; jj < 2; ++jj)
#pragma unroll
      for (int r = 0; r < 4; ++r) {
        int p = mi * 16 + quad * 4 + r;
        int j = (2 * w + jj) * 16 + mh;
        float y = (float)Y[p * 136 + j];
        float sv = fmaf(Dc, y, acc[mi][jj][r]);
        float g = 0.5f * sv * (1.0f + erff(sv * 0.70710678118654752f));
        ub[mi][jj][r] = (bf16)g;
      }
  __syncthreads();   // all Y/H reads complete
#pragma unroll
  for (int mi = 0; mi < 8; ++mi)
#pragma unroll
    for (int jj = 0; jj < 2; ++jj)
#pragma unroll
      for (int r = 0; r < 4; ++r) {
        int p = mi * 16 + quad * 4 + r;
        int j = (2 * w + jj) * 16 + mh;
        Y[p * 136 + j] = ub[mi][jj][r];
      }
  __syncthreads();
  // coalesced writeout U[b][c][t]
  bf16* Uc = U + (size_t)(b * cC + c) * cT;
#pragma unroll
  for (int it = 0; it < 16; ++it) {
    int i4 = tid + it * 256;
    if (i4 < 4000) {
      int t = i4 * 4, p = t >> 7, j = t & 127;
      *(bf16x4*)(Uc + t) = *(bf16x4*)&Y[p * 136 + j];
    }
  }
}

// ---------------- gemm2: z = W_out @ u (+bias, GLU, +residual), U in [b][c][t] ----------------
// Block: 64 tokens x all 512 out-channels; U tile LDS-transposed to [t][c].
__global__ __launch_bounds__(256, 2)
void gemm2_kernel(const bf16* __restrict__ U, const bf16* __restrict__ Wb,
                  const float* __restrict__ b_out, const float* __restrict__ x,
                  float* __restrict__ out) {
  __shared__ __align__(16) bf16 Ut[64 * 264];
  int bx = blockIdx.x;        // 0..1999
  int tb = bx % 250, b = bx / 250;
  int t0 = tb * 64;
  int tid = threadIdx.x, lane = tid & 63, w = tid >> 6, quad = lane >> 4, mh = lane & 15;
  // stage: thread = channel c, read 64 t, transpose into Ut[t][c]
  {
    const bf16* src = U + (size_t)(b * cC + tid) * cT + t0;
#pragma unroll
    for (int g = 0; g < 8; ++g) {
      bf16x8 v = *(const bf16x8*)(src + g * 8);
#pragma unroll
      for (int k = 0; k < 8; ++k) Ut[(g * 8 + k) * 264 + tid] = v[k];
    }
  }
  __syncthreads();
  floatx4 a1[4][4], a2[4][4];
#pragma unroll
  for (int oj = 0; oj < 4; ++oj)
#pragma unroll
    for (int tt = 0; tt < 4; ++tt) {
      a1[oj][tt] = (floatx4){0.f, 0.f, 0.f, 0.f};
      a2[oj][tt] = (floatx4){0.f, 0.f, 0.f, 0.f};
    }
#pragma unroll
  for (int kk = 0; kk < 8; ++kk) {
    int ko = kk * 32 + quad * 8;
    bf16x8 wf1[4], wf2[4];
#pragma unroll
    for (int oj = 0; oj < 4; ++oj) {
      int o = w * 64 + oj * 16 + mh;
      wf1[oj] = *(const bf16x8*)(Wb + (size_t)o * 256 + ko);
      wf2[oj] = *(const bf16x8*)(Wb + (size_t)(o + 256) * 256 + ko);
    }
#pragma unroll
    for (int tt = 0; tt < 4; ++tt) {
      bf16x8 uf = *(bf16x8*)&Ut[(tt * 16 + mh) * 264 + ko];
#pragma unroll
      for (int oj = 0; oj < 4; ++oj) {
        a1[oj][tt] = __builtin_amdgcn_mfma_f32_16x16x32_bf16(wf1[oj], uf, a1[oj][tt], 0, 0, 0);
        a2[oj][tt] = __builtin_amdgcn_mfma_f32_16x16x32_bf16(wf2[oj], uf, a2[oj][tt], 0, 0, 0);
      }
    }
  }
#pragma unroll
  for (int oj = 0; oj < 4; ++oj)
#pragma unroll
    for (int tt = 0; tt < 4; ++tt)
#pragma unroll
      for (int r = 0; r < 4; ++r) {
        int o = w * 64 + oj * 16 + quad * 4 + r;
        int t = t0 + tt * 16 + mh;
        float z1 = a1[oj][tt][r] + b_out[o];
        float z2 = a2[oj][tt][r] + b_out[o + 256];
        float sg = 1.0f / (1.0f + expf(-z2));
        size_t idx = (size_t)(b * cC + o) * cT + t;
        out[idx] = x[idx] + z1 * sg;
      }
}

extern "C" void kernel_launch(void* const* d_in, const int* in_sizes, int n_in,
                              void* d_out, int out_size, void* d_ws, size_t ws_size,
                              hipStream_t stream) {
  const float* x          = (const float*)d_in[0];
  const float* gamma      = (const float*)d_in[1];
  const float* beta       = (const float*)d_in[2];
  const float* prelu_w    = (const float*)d_in[3];
  const float* log_dt     = (const float*)d_in[4];
  const float* log_A_real = (const float*)d_in[5];
  const float* A_imag     = (const float*)d_in[6];
  const float* C_re       = (const float*)d_in[7];
  const float* C_im       = (const float*)d_in[8];
  const float* Dp         = (const float*)d_in[9];
  const float* W_out      = (const float*)d_in[10];
  const float* b_out      = (const float*)d_in[11];
  float* out = (float*)d_out;
  char* ws = (char*)d_ws;

  float* meanp = (float*)(ws + kMean);
  float* rstdp = (float*)(ws + kRstd);
  float* wlr   = (float*)(ws + kWlr);
  float* wli   = (float*)(ws + kWli);
  bf16*  Wb    = (bf16*)(ws + kWb);
  bf16*  Lt    = (bf16*)(ws + kLt);
  bf16*  Et    = (bf16*)(ws + kEt);
  bf16*  Vt    = (bf16*)(ws + kVt);
  bf16*  U     = (bf16*)(ws + kU);

  prepW_kernel<<<512, 256, 0, stream>>>(W_out, Wb);
  prep2_kernel<<<256, 128, 0, stream>>>(log_dt, log_A_real, A_imag, C_re, C_im,
                                        wlr, wli, Lt, Et, Vt);
  stats_kernel<<<(cB * cT) / 256, 256, 0, stream>>>(x, meanp, rstdp);
  scanM_kernel<<<cB * cC, 256, 0, stream>>>(x, meanp, rstdp, gamma, beta, prelu_w,
                                            Dp, wlr, wli, Lt, Et, Vt, U);
  gemm2_kernel<<<cB * (cT / 64), 256, 0, stream>>>(U, Wb, b_out, x, out);
}